// Round 4
// baseline (534.819 us; speedup 1.0000x reference)
//
#include <hip/hip_runtime.h>

namespace {
constexpr int NBb = 8;                 // n_batch after /T
constexpr int TT  = 8;                 // T
constexpr int TOo = 8;                 // T_OUT
constexpr int CC  = 256;
constexpr int GG  = 4;
constexpr int CPG = 64;
constexpr int HHH = 56;
constexpr int WWW = 56;
constexpr int HWs = HHH * WWW;         // 3136
constexpr long CHW = (long)CC * HWs;   // 802816
constexpr int NC  = (TT - 1) * 9;      // 63
constexpr int NW  = 4;                 // waves per block
constexpr int CPW = CPG / NW;          // 16 channels per wave
}

__global__ __launch_bounds__(256, 4)
void corr_fusion(const float* __restrict__ x,
                 const float* __restrict__ conv_w,
                 const float* __restrict__ conv_b,
                 float* __restrict__ out)
{
    // LDS: reused as (a) corr reduction buffer [63][64], (b) wx exchange [64][64]
    __shared__ float smem[64][64];     // 16 KB

    const int tid  = threadIdx.x;
    const int w    = tid & 63;                   // lane = w (active w<56)
    const int wave = tid >> 6;                   // 0..3
    const int wc   = w < WWW - 1 ? w : WWW - 1;  // clamped for addressing
    const int h  = blockIdx.x;
    const int g  = blockIdx.y;
    const int n  = blockIdx.z;
    const int hm = h > 0 ? h - 1 : 0;            // replication pad vertical
    const int hp = h < HHH - 1 ? h + 1 : HHH - 1;

    const int offh = h  * WWW + wc;
    const int offm = hm * WWW + wc;
    const int offp = hp * WWW + wc;

    // zero the corr reduction region
    for (int i = tid; i < NC * 64; i += 256) (&smem[0][0])[i] = 0.0f;
    __syncthreads();

    // ---------------- phase 1: 9-way shifted correlation (c-split) ----------------
    float corr[NC];
#pragma unroll
    for (int i = 0; i < NC; ++i) corr[i] = 0.0f;

    const float* xg = x + (long)n * TT * CHW + (long)g * CPG * HWs;

    for (int c = wave * CPW; c < wave * CPW + CPW; ++c) {
        const float* xc = xg + (long)c * HWs;
        float rh[TT], rm[TT - 1], rp[TT - 1];
#pragma unroll
        for (int t = 0; t < TT; ++t) rh[t] = xc[(long)t * CHW + offh];
#pragma unroll
        for (int t = 1; t < TT; ++t) {
            rm[t - 1] = xc[(long)t * CHW + offm];
            rp[t - 1] = xc[(long)t * CHW + offp];
        }
#pragma unroll
        for (int t = 0; t < TT - 1; ++t) {
            const float a = rh[t];
#pragma unroll
            for (int di = 0; di < 3; ++di) {
                float bc = (di == 0) ? rm[t] : (di == 1) ? rh[t + 1] : rp[t];
                float bl = __shfl_up(bc, 1);     // value at w-1
                if (w == 0) bl = bc;             // replication pad left
                float br = __shfl_down(bc, 1);   // value at w+1
                if (w == WWW - 1) br = bc;       // replication pad right
                const int base = t * 9 + di * 3;
                corr[base + 0] = fmaf(a, bl, corr[base + 0]);
                corr[base + 1] = fmaf(a, bc, corr[base + 1]);
                corr[base + 2] = fmaf(a, br, corr[base + 2]);
            }
        }
    }

    // reduce partial corr across the 4 waves (ds_add_f32; order-dep FP ok at tol)
#pragma unroll
    for (int i = 0; i < NC; ++i) atomicAdd(&smem[i][w], corr[i]);
    __syncthreads();

    // pull the full corr back into registers (all waves need all 63)
    float corr_r[NC];
#pragma unroll
    for (int i = 0; i < NC; ++i) corr_r[i] = smem[i][w];
    __syncthreads();   // everyone done reading before we overwrite with wx

    // ---------------- grouped 1x1 conv: o-split, 16 outputs per wave ----------------
    const float* cw = conv_w + (long)g * (TOo * TT) * NC;
    const float* cb = conv_b + g * (TOo * TT);
    float wx16[CPW];
#pragma unroll
    for (int oo = 0; oo < CPW; ++oo) {
        const int o = wave * CPW + oo;
        float s = cb[o];
#pragma unroll
        for (int i = 0; i < NC; ++i) s = fmaf(cw[o * NC + i], corr_r[i], s);
        wx16[oo] = s;
    }
#pragma unroll
    for (int oo = 0; oo < CPW; ++oo) smem[wave * CPW + oo][w] = wx16[oo];
    __syncthreads();

    float wxr[TOo * TT];
#pragma unroll
    for (int o = 0; o < TOo * TT; ++o) wxr[o] = smem[o][w];

    // ---------------- phase 2: weighted segment-sum + residual (cp-split) ----------------
    const float* xn = x   + (long)n * TT  * CHW;
    float*       on = out + (long)n * TOo * CHW;
    for (int cpi = 0; cpi < CPW; ++cpi) {
        const int cp = wave * CPW + cpi;
        const float* xc = xn + (long)(cp * GG + g) * HWs + offh;
        float xv[TT];
#pragma unroll
        for (int t = 0; t < TT; ++t) xv[t] = xc[(long)t * CHW];
        if (w < WWW) {
            float* oc = on + (long)(g * CPG + cp) * HWs + h * WWW + w;
#pragma unroll
            for (int to = 0; to < TOo; ++to) {
                float s = xv[to];   // residual (i_in[to] == to)
#pragma unroll
                for (int t = 0; t < TT; ++t) s = fmaf(wxr[to * TT + t], xv[t], s);
                oc[(long)to * CHW] = s;
            }
        }
    }
}

extern "C" void kernel_launch(void* const* d_in, const int* in_sizes, int n_in,
                              void* d_out, int out_size, void* d_ws, size_t ws_size,
                              hipStream_t stream) {
    const float* x  = (const float*)d_in[0];
    const float* cw = (const float*)d_in[1];
    const float* cb = (const float*)d_in[2];
    float* out = (float*)d_out;

    dim3 grid(HHH, GG, NBb);   // (h, g, n) = (56, 4, 8), 4 waves per block
    dim3 block(256);
    hipLaunchKernelGGL(corr_fusion, grid, block, 0, stream, x, cw, cb, out);
}

// Round 5
// 516.730 us; speedup vs baseline: 1.0350x; 1.0350x over previous
//
#include <hip/hip_runtime.h>

namespace {
constexpr int NBb = 8;                 // n_batch after /T
constexpr int TT  = 8;                 // T
constexpr int TOo = 8;                 // T_OUT
constexpr int CC  = 256;
constexpr int GG  = 4;
constexpr int CPG = 64;
constexpr int HHH = 56;
constexpr int WWW = 56;
constexpr int HWs = HHH * WWW;         // 3136
constexpr long CHW = (long)CC * HWs;   // 802816
constexpr int NC  = (TT - 1) * 9;      // 63
constexpr long CORR_ELEMS = (long)NBb * GG * NC * HWs;   // 25.3 MB as fp32
}

// ---------------------------------------------------------------------------
// Kernel A: 9-way shifted correlation, one wave per (n, g, t, h) row.
// corr[n][g][t*9 + di*3 + dj][h][w] = sum_c x[t,gc,h,w] * x[t+1,gc,h+di-1,w+dj-1]
// ---------------------------------------------------------------------------
__global__ __launch_bounds__(64, 8)
void corr_k(const float* __restrict__ x, float* __restrict__ corr)
{
    // XCD-bijective swizzle: nwg = 392*4*8 = 12544 (divisible by 8).
    // XCD k gets a contiguous span of work (keeps adjacent-h halo reuse in its L2).
    const int lid = blockIdx.x + 392 * (blockIdx.y + 4 * blockIdx.z);
    const int wg  = (lid & 7) * 1568 + (lid >> 3);
    const int bx  = wg % 392;
    const int rem = wg / 392;          // 0..31
    const int g   = rem & 3;
    const int n   = rem >> 2;
    const int t   = bx / HHH;          // 0..6
    const int h   = bx % HHH;

    const int w  = threadIdx.x;                  // lane = w (active w<56)
    const int wc = w < WWW - 1 ? w : WWW - 1;    // clamped (right replication pad)
    const int hm = h > 0 ? h - 1 : 0;
    const int hp = h < HHH - 1 ? h + 1 : HHH - 1;

    const float* xa = x + (long)n * TT * CHW + (long)g * CPG * HWs + (long)t * CHW;
    const float* xb = xa + CHW;                  // frame t+1
    const int offh = h  * WWW + wc;
    const int offm = hm * WWW + wc;
    const int offp = hp * WWW + wc;

    float acc[9];
#pragma unroll
    for (int k = 0; k < 9; ++k) acc[k] = 0.0f;

#pragma unroll 4
    for (int c = 0; c < CPG; ++c) {
        const long co = (long)c * HWs;
        const float a  = xa[co + offh];
        const float bm = xb[co + offm];
        const float bc = xb[co + offh];
        const float bp = xb[co + offp];
        float bml = __shfl_up(bm, 1), bmr = __shfl_down(bm, 1);
        float bcl = __shfl_up(bc, 1), bcr = __shfl_down(bc, 1);
        float bpl = __shfl_up(bp, 1), bpr = __shfl_down(bp, 1);
        if (w == 0) { bml = bm; bcl = bc; bpl = bp; }
        // right edge: lane 55 pulls lane 56, which holds the clamped w=55 value
        acc[0] = fmaf(a, bml, acc[0]); acc[1] = fmaf(a, bm, acc[1]); acc[2] = fmaf(a, bmr, acc[2]);
        acc[3] = fmaf(a, bcl, acc[3]); acc[4] = fmaf(a, bc, acc[4]); acc[5] = fmaf(a, bcr, acc[5]);
        acc[6] = fmaf(a, bpl, acc[6]); acc[7] = fmaf(a, bp, acc[7]); acc[8] = fmaf(a, bpr, acc[8]);
    }

    if (w < WWW) {
        float* co = corr + ((((long)n * GG + g) * 7 + t) * 9) * HWs + h * WWW + w;
#pragma unroll
        for (int k = 0; k < 9; ++k) co[(long)k * HWs] = acc[k];
    }
}

// ---------------------------------------------------------------------------
// Kernel B: grouped 1x1 conv (corr[63] -> wx[64]) + weighted segment-sum + residual.
// Block = (h, g, n), 4 waves, one barrier (LDS wx exchange).
// ---------------------------------------------------------------------------
__global__ __launch_bounds__(256, 2)
void fuse_k(const float* __restrict__ x, const float* __restrict__ corr,
            const float* __restrict__ conv_w, const float* __restrict__ conv_b,
            float* __restrict__ out)
{
    __shared__ float swx[64][64];      // 16 KB wx exchange

    const int tid  = threadIdx.x;
    const int w    = tid & 63;
    const int wave = tid >> 6;                   // 0..3
    const int wc   = w < WWW - 1 ? w : WWW - 1;
    const int h = blockIdx.x;
    const int g = blockIdx.y;
    const int n = blockIdx.z;

    // each wave loads all 63 corr rows (redundant x4 within block -> L1 hits)
    float cr[NC];
    const float* cbase = corr + (((long)n * GG + g) * NC) * HWs + h * WWW;
#pragma unroll
    for (int i = 0; i < NC; ++i) cr[i] = cbase[(long)i * HWs + wc];

    // conv: this wave computes outputs [wave*16, wave*16+16)
    const float* cw = conv_w + (long)g * (TOo * TT) * NC;
    const float* cb = conv_b + g * (TOo * TT);
#pragma unroll
    for (int oo = 0; oo < 16; ++oo) {
        const int o = wave * 16 + oo;
        float s = cb[o];
#pragma unroll
        for (int i = 0; i < NC; ++i) s = fmaf(cw[o * NC + i], cr[i], s);
        swx[o][w] = s;
    }
    __syncthreads();

    float wxr[TOo * TT];
#pragma unroll
    for (int o = 0; o < TOo * TT; ++o) wxr[o] = swx[o][w];

    // phase 2: weighted segment-sum + residual, 16 cp per wave
    const float* xn = x   + (long)n * TT  * CHW;
    float*       on = out + (long)n * TOo * CHW;
    for (int cpi = 0; cpi < 16; ++cpi) {
        const int cp = wave * 16 + cpi;
        const float* xc = xn + (long)(cp * GG + g) * HWs + h * WWW + wc;
        float xv[TT];
#pragma unroll
        for (int t = 0; t < TT; ++t) xv[t] = xc[(long)t * CHW];
        if (w < WWW) {
            float* oc = on + (long)(g * CPG + cp) * HWs + h * WWW + w;
#pragma unroll
            for (int to = 0; to < TOo; ++to) {
                float s = xv[to];   // residual (i_in[to] == to)
#pragma unroll
                for (int t = 0; t < TT; ++t) s = fmaf(wxr[to * TT + t], xv[t], s);
                oc[(long)to * CHW] = s;
            }
        }
    }
}

// ---------------------------------------------------------------------------
// Fallback: the proven single-kernel R1 version (used only if ws is too small).
// ---------------------------------------------------------------------------
__global__ __launch_bounds__(64, 2)
void corr_fusion_mono(const float* __restrict__ x,
                      const float* __restrict__ conv_w,
                      const float* __restrict__ conv_b,
                      float* __restrict__ out)
{
    const int w  = threadIdx.x;
    const int wc = w < WWW - 1 ? w : WWW - 1;
    const int h  = blockIdx.x;
    const int g  = blockIdx.y;
    const int n  = blockIdx.z;
    const int hm = h > 0 ? h - 1 : 0;
    const int hp = h < HHH - 1 ? h + 1 : HHH - 1;

    const int offh = h  * WWW + wc;
    const int offm = hm * WWW + wc;
    const int offp = hp * WWW + wc;

    float corr[NC];
#pragma unroll
    for (int i = 0; i < NC; ++i) corr[i] = 0.0f;

    const float* xg = x + (long)n * TT * CHW + (long)g * CPG * HWs;

    for (int c = 0; c < CPG; ++c) {
        const float* xc = xg + (long)c * HWs;
        float rh[TT], rm[TT - 1], rp[TT - 1];
#pragma unroll
        for (int t = 0; t < TT; ++t) rh[t] = xc[(long)t * CHW + offh];
#pragma unroll
        for (int t = 1; t < TT; ++t) {
            rm[t - 1] = xc[(long)t * CHW + offm];
            rp[t - 1] = xc[(long)t * CHW + offp];
        }
#pragma unroll
        for (int t = 0; t < TT - 1; ++t) {
            const float a = rh[t];
#pragma unroll
            for (int di = 0; di < 3; ++di) {
                float bc = (di == 0) ? rm[t] : (di == 1) ? rh[t + 1] : rp[t];
                float bl = __shfl_up(bc, 1);
                if (w == 0) bl = bc;
                float br = __shfl_down(bc, 1);
                if (w == WWW - 1) br = bc;
                const int base = t * 9 + di * 3;
                corr[base + 0] = fmaf(a, bl, corr[base + 0]);
                corr[base + 1] = fmaf(a, bc, corr[base + 1]);
                corr[base + 2] = fmaf(a, br, corr[base + 2]);
            }
        }
    }

    const float* cw = conv_w + (long)g * (TOo * TT) * NC;
    const float* cb = conv_b + g * (TOo * TT);
    float wx[TOo * TT];
#pragma unroll
    for (int o = 0; o < TOo * TT; ++o) {
        float s = cb[o];
#pragma unroll
        for (int i = 0; i < NC; ++i) s = fmaf(cw[o * NC + i], corr[i], s);
        wx[o] = s;
    }

    const float* xn = x   + (long)n * TT  * CHW;
    float*       on = out + (long)n * TOo * CHW;
    for (int cp = 0; cp < CPG; ++cp) {
        const float* xc = xn + (long)(cp * GG + g) * HWs + offh;
        float xv[TT];
#pragma unroll
        for (int t = 0; t < TT; ++t) xv[t] = xc[(long)t * CHW];
        if (w < WWW) {
            float* oc = on + (long)(g * CPG + cp) * HWs + h * WWW + w;
#pragma unroll
            for (int to = 0; to < TOo; ++to) {
                float s = xv[to];
#pragma unroll
                for (int t = 0; t < TT; ++t) s = fmaf(wx[to * TT + t], xv[t], s);
                oc[(long)to * CHW] = s;
            }
        }
    }
}

extern "C" void kernel_launch(void* const* d_in, const int* in_sizes, int n_in,
                              void* d_out, int out_size, void* d_ws, size_t ws_size,
                              hipStream_t stream) {
    const float* x  = (const float*)d_in[0];
    const float* cw = (const float*)d_in[1];
    const float* cb = (const float*)d_in[2];
    float* out = (float*)d_out;

    if (ws_size >= CORR_ELEMS * sizeof(float)) {
        float* corr = (float*)d_ws;
        dim3 gridA(7 * HHH, GG, NBb);   // (t*h, g, n) = 12544 single-wave blocks
        hipLaunchKernelGGL(corr_k, gridA, dim3(64), 0, stream, x, corr);
        dim3 gridB(HHH, GG, NBb);       // (h, g, n), 4 waves per block
        hipLaunchKernelGGL(fuse_k, gridB, dim3(256), 0, stream, x, corr, cw, cb, out);
    } else {
        dim3 grid(HHH, GG, NBb);
        hipLaunchKernelGGL(corr_fusion_mono, grid, dim3(64), 0, stream, x, cw, cb, out);
    }
}

// Round 6
// 492.263 us; speedup vs baseline: 1.0864x; 1.0497x over previous
//
#include <hip/hip_runtime.h>

namespace {
constexpr int NBb = 8;                 // n_batch after /T
constexpr int TT  = 8;                 // T
constexpr int TOo = 8;                 // T_OUT
constexpr int CC  = 256;
constexpr int GG  = 4;
constexpr int CPG = 64;
constexpr int HHH = 56;
constexpr int WWW = 56;
constexpr int HWs = HHH * WWW;         // 3136
constexpr long CHW = (long)CC * HWs;   // 802816
constexpr int NC  = (TT - 1) * 9;      // 63
constexpr long CORR_ELEMS = (long)NBb * GG * NC * HWs;         // 6,322,176
constexpr long WX_ELEMS   = (long)NBb * GG * (TOo * TT) * HWs; // 6,422,528
}

// ---------------------------------------------------------------------------
// Kernel 1: 9-way shifted correlation, one wave per (n, g, t, h) row.
// corr[n][g][t*9 + di*3 + dj][h][w] = sum_c x[t,gc,h,w] * x[t+1,gc,h+di-1,w+dj-1]
// ---------------------------------------------------------------------------
__global__ __launch_bounds__(64, 8)
void corr_k(const float* __restrict__ x, float* __restrict__ corr)
{
    // XCD-bijective swizzle: nwg = 392*4*8 = 12544 (divisible by 8).
    const int lid = blockIdx.x + 392 * (blockIdx.y + 4 * blockIdx.z);
    const int wg  = (lid & 7) * 1568 + (lid >> 3);
    const int bx  = wg % 392;
    const int rem = wg / 392;          // 0..31
    const int g   = rem & 3;
    const int n   = rem >> 2;
    const int t   = bx / HHH;          // 0..6
    const int h   = bx % HHH;

    const int w  = threadIdx.x;                  // lane = w (active w<56)
    const int wc = w < WWW - 1 ? w : WWW - 1;    // clamped (right replication pad)
    const int hm = h > 0 ? h - 1 : 0;
    const int hp = h < HHH - 1 ? h + 1 : HHH - 1;

    const float* xa = x + (long)n * TT * CHW + (long)g * CPG * HWs + (long)t * CHW;
    const float* xb = xa + CHW;                  // frame t+1
    const int offh = h  * WWW + wc;
    const int offm = hm * WWW + wc;
    const int offp = hp * WWW + wc;

    float acc[9];
#pragma unroll
    for (int k = 0; k < 9; ++k) acc[k] = 0.0f;

#pragma unroll 4
    for (int c = 0; c < CPG; ++c) {
        const long co = (long)c * HWs;
        const float a  = xa[co + offh];
        const float bm = xb[co + offm];
        const float bc = xb[co + offh];
        const float bp = xb[co + offp];
        float bml = __shfl_up(bm, 1), bmr = __shfl_down(bm, 1);
        float bcl = __shfl_up(bc, 1), bcr = __shfl_down(bc, 1);
        float bpl = __shfl_up(bp, 1), bpr = __shfl_down(bp, 1);
        if (w == 0) { bml = bm; bcl = bc; bpl = bp; }
        // right edge: lane 55 pulls lane 56, which holds the clamped w=55 value
        acc[0] = fmaf(a, bml, acc[0]); acc[1] = fmaf(a, bm, acc[1]); acc[2] = fmaf(a, bmr, acc[2]);
        acc[3] = fmaf(a, bcl, acc[3]); acc[4] = fmaf(a, bc, acc[4]); acc[5] = fmaf(a, bcr, acc[5]);
        acc[6] = fmaf(a, bpl, acc[6]); acc[7] = fmaf(a, bp, acc[7]); acc[8] = fmaf(a, bpr, acc[8]);
    }

    if (w < WWW) {
        float* co = corr + ((((long)n * GG + g) * 7 + t) * 9) * HWs + h * WWW + w;
#pragma unroll
        for (int k = 0; k < 9; ++k) co[(long)k * HWs] = acc[k];
    }
}

// ---------------------------------------------------------------------------
// Kernel 2: grouped 1x1 conv per pixel: wx[o] = b[o] + sum_i w[o][i]*corr[i].
// One wave per (n, g, ochunk, h); 16 outputs per wave. No LDS, no barrier.
// ---------------------------------------------------------------------------
__global__ __launch_bounds__(64, 4)
void conv_k(const float* __restrict__ corr,
            const float* __restrict__ conv_w, const float* __restrict__ conv_b,
            float* __restrict__ wxws)
{
    const int w   = threadIdx.x;
    const int wc  = w < WWW - 1 ? w : WWW - 1;
    const int h   = blockIdx.x;
    const int by  = blockIdx.y;        // g*4 + ochunk
    const int g   = by >> 2;
    const int och = by & 3;
    const int n   = blockIdx.z;

    const float* cbase = corr + (((long)n * GG + g) * NC) * HWs + h * WWW + wc;
    float cr[NC];
#pragma unroll
    for (int i = 0; i < NC; ++i) cr[i] = cbase[(long)i * HWs];

    const float* cw = conv_w + (long)g * (TOo * TT) * NC;
    const float* cb = conv_b + g * (TOo * TT);
    float* wbase = wxws + (((long)n * GG + g) * (TOo * TT)) * HWs + h * WWW + w;

#pragma unroll
    for (int oo = 0; oo < 16; ++oo) {
        const int o = och * 16 + oo;
        float s = cb[o];
#pragma unroll
        for (int i = 0; i < NC; ++i) s = fmaf(cw[o * NC + i], cr[i], s);
        if (w < WWW) wbase[(long)o * HWs] = s;
    }
}

// ---------------------------------------------------------------------------
// Kernel 3: weighted segment-sum + residual.
// out[n*8+to, g*64+cp, h, w] = x[n*8+to, cp*4+g, h, w]
//                            + sum_t wx[n,g,to*8+t,h,w] * x[n*8+t, cp*4+g, h, w]
// One wave per (n, g, cpchunk, h); 8 cp per wave. No LDS, no barrier.
// ---------------------------------------------------------------------------
__global__ __launch_bounds__(64, 4)
void seg_k(const float* __restrict__ x, const float* __restrict__ wxws,
           float* __restrict__ out)
{
    const int w   = threadIdx.x;
    const int wc  = w < WWW - 1 ? w : WWW - 1;
    const int h   = blockIdx.x;
    const int by  = blockIdx.y;        // g*8 + cpchunk
    const int g   = by >> 3;
    const int cch = by & 7;
    const int n   = blockIdx.z;

    const float* wbase = wxws + (((long)n * GG + g) * (TOo * TT)) * HWs + h * WWW + wc;
    float wxr[TOo * TT];
#pragma unroll
    for (int o = 0; o < TOo * TT; ++o) wxr[o] = wbase[(long)o * HWs];

    const float* xn = x   + (long)n * TT  * CHW;
    float*       on = out + (long)n * TOo * CHW;

#pragma unroll
    for (int cpi = 0; cpi < 8; ++cpi) {
        const int cp = cch * 8 + cpi;
        const float* xc = xn + (long)(cp * GG + g) * HWs + h * WWW + wc;
        float xv[TT];
#pragma unroll
        for (int t = 0; t < TT; ++t) xv[t] = xc[(long)t * CHW];
        if (w < WWW) {
            float* oc = on + (long)(g * CPG + cp) * HWs + h * WWW + w;
#pragma unroll
            for (int to = 0; to < TOo; ++to) {
                float s = xv[to];   // residual (i_in[to] == to)
#pragma unroll
                for (int t = 0; t < TT; ++t) s = fmaf(wxr[to * TT + t], xv[t], s);
                oc[(long)to * CHW] = s;
            }
        }
    }
}

// ---------------------------------------------------------------------------
// Fallback A (ws >= corr only): R5's fused conv+segsum kernel.
// ---------------------------------------------------------------------------
__global__ __launch_bounds__(256, 2)
void fuse_k(const float* __restrict__ x, const float* __restrict__ corr,
            const float* __restrict__ conv_w, const float* __restrict__ conv_b,
            float* __restrict__ out)
{
    __shared__ float swx[64][64];

    const int tid  = threadIdx.x;
    const int w    = tid & 63;
    const int wave = tid >> 6;
    const int wc   = w < WWW - 1 ? w : WWW - 1;
    const int h = blockIdx.x;
    const int g = blockIdx.y;
    const int n = blockIdx.z;

    float cr[NC];
    const float* cbase = corr + (((long)n * GG + g) * NC) * HWs + h * WWW;
#pragma unroll
    for (int i = 0; i < NC; ++i) cr[i] = cbase[(long)i * HWs + wc];

    const float* cw = conv_w + (long)g * (TOo * TT) * NC;
    const float* cb = conv_b + g * (TOo * TT);
#pragma unroll
    for (int oo = 0; oo < 16; ++oo) {
        const int o = wave * 16 + oo;
        float s = cb[o];
#pragma unroll
        for (int i = 0; i < NC; ++i) s = fmaf(cw[o * NC + i], cr[i], s);
        swx[o][w] = s;
    }
    __syncthreads();

    float wxr[TOo * TT];
#pragma unroll
    for (int o = 0; o < TOo * TT; ++o) wxr[o] = swx[o][w];

    const float* xn = x   + (long)n * TT  * CHW;
    float*       on = out + (long)n * TOo * CHW;
    for (int cpi = 0; cpi < 16; ++cpi) {
        const int cp = wave * 16 + cpi;
        const float* xc = xn + (long)(cp * GG + g) * HWs + h * WWW + wc;
        float xv[TT];
#pragma unroll
        for (int t = 0; t < TT; ++t) xv[t] = xc[(long)t * CHW];
        if (w < WWW) {
            float* oc = on + (long)(g * CPG + cp) * HWs + h * WWW + w;
#pragma unroll
            for (int to = 0; to < TOo; ++to) {
                float s = xv[to];
#pragma unroll
                for (int t = 0; t < TT; ++t) s = fmaf(wxr[to * TT + t], xv[t], s);
                oc[(long)to * CHW] = s;
            }
        }
    }
}

// ---------------------------------------------------------------------------
// Fallback B (tiny ws): the proven single-kernel R1 version.
// ---------------------------------------------------------------------------
__global__ __launch_bounds__(64, 2)
void corr_fusion_mono(const float* __restrict__ x,
                      const float* __restrict__ conv_w,
                      const float* __restrict__ conv_b,
                      float* __restrict__ out)
{
    const int w  = threadIdx.x;
    const int wc = w < WWW - 1 ? w : WWW - 1;
    const int h  = blockIdx.x;
    const int g  = blockIdx.y;
    const int n  = blockIdx.z;
    const int hm = h > 0 ? h - 1 : 0;
    const int hp = h < HHH - 1 ? h + 1 : HHH - 1;

    const int offh = h  * WWW + wc;
    const int offm = hm * WWW + wc;
    const int offp = hp * WWW + wc;

    float corr[NC];
#pragma unroll
    for (int i = 0; i < NC; ++i) corr[i] = 0.0f;

    const float* xg = x + (long)n * TT * CHW + (long)g * CPG * HWs;

    for (int c = 0; c < CPG; ++c) {
        const float* xc = xg + (long)c * HWs;
        float rh[TT], rm[TT - 1], rp[TT - 1];
#pragma unroll
        for (int t = 0; t < TT; ++t) rh[t] = xc[(long)t * CHW + offh];
#pragma unroll
        for (int t = 1; t < TT; ++t) {
            rm[t - 1] = xc[(long)t * CHW + offm];
            rp[t - 1] = xc[(long)t * CHW + offp];
        }
#pragma unroll
        for (int t = 0; t < TT - 1; ++t) {
            const float a = rh[t];
#pragma unroll
            for (int di = 0; di < 3; ++di) {
                float bc = (di == 0) ? rm[t] : (di == 1) ? rh[t + 1] : rp[t];
                float bl = __shfl_up(bc, 1);
                if (w == 0) bl = bc;
                float br = __shfl_down(bc, 1);
                if (w == WWW - 1) br = bc;
                const int base = t * 9 + di * 3;
                corr[base + 0] = fmaf(a, bl, corr[base + 0]);
                corr[base + 1] = fmaf(a, bc, corr[base + 1]);
                corr[base + 2] = fmaf(a, br, corr[base + 2]);
            }
        }
    }

    const float* cw = conv_w + (long)g * (TOo * TT) * NC;
    const float* cb = conv_b + g * (TOo * TT);
    float wx[TOo * TT];
#pragma unroll
    for (int o = 0; o < TOo * TT; ++o) {
        float s = cb[o];
#pragma unroll
        for (int i = 0; i < NC; ++i) s = fmaf(cw[o * NC + i], corr[i], s);
        wx[o] = s;
    }

    const float* xn = x   + (long)n * TT  * CHW;
    float*       on = out + (long)n * TOo * CHW;
    for (int cp = 0; cp < CPG; ++cp) {
        const float* xc = xn + (long)(cp * GG + g) * HWs + offh;
        float xv[TT];
#pragma unroll
        for (int t = 0; t < TT; ++t) xv[t] = xc[(long)t * CHW];
        if (w < WWW) {
            float* oc = on + (long)(g * CPG + cp) * HWs + h * WWW + w;
#pragma unroll
            for (int to = 0; to < TOo; ++to) {
                float s = xv[to];
#pragma unroll
                for (int t = 0; t < TT; ++t) s = fmaf(wx[to * TT + t], xv[t], s);
                oc[(long)to * CHW] = s;
            }
        }
    }
}

extern "C" void kernel_launch(void* const* d_in, const int* in_sizes, int n_in,
                              void* d_out, int out_size, void* d_ws, size_t ws_size,
                              hipStream_t stream) {
    const float* x  = (const float*)d_in[0];
    const float* cw = (const float*)d_in[1];
    const float* cb = (const float*)d_in[2];
    float* out = (float*)d_out;

    if (ws_size >= (CORR_ELEMS + WX_ELEMS) * sizeof(float)) {
        float* corr = (float*)d_ws;
        float* wxws = corr + CORR_ELEMS;
        dim3 gridA(7 * HHH, GG, NBb);        // 12544 single-wave blocks
        hipLaunchKernelGGL(corr_k, gridA, dim3(64), 0, stream, x, corr);
        dim3 gridC(HHH, GG * 4, NBb);        // 7168 single-wave blocks
        hipLaunchKernelGGL(conv_k, gridC, dim3(64), 0, stream, corr, cw, cb, wxws);
        dim3 gridS(HHH, GG * 8, NBb);        // 14336 single-wave blocks
        hipLaunchKernelGGL(seg_k, gridS, dim3(64), 0, stream, x, wxws, out);
    } else if (ws_size >= CORR_ELEMS * sizeof(float)) {
        float* corr = (float*)d_ws;
        dim3 gridA(7 * HHH, GG, NBb);
        hipLaunchKernelGGL(corr_k, gridA, dim3(64), 0, stream, x, corr);
        dim3 gridB(HHH, GG, NBb);
        hipLaunchKernelGGL(fuse_k, gridB, dim3(256), 0, stream, x, corr, cw, cb, out);
    } else {
        dim3 grid(HHH, GG, NBb);
        hipLaunchKernelGGL(corr_fusion_mono, grid, dim3(64), 0, stream, x, cw, cb, out);
    }
}

// Round 8
// 458.657 us; speedup vs baseline: 1.1661x; 1.0733x over previous
//
#include <hip/hip_runtime.h>

namespace {
constexpr int NBb = 8;                 // n_batch after /T
constexpr int TT  = 8;                 // T
constexpr int TOo = 8;                 // T_OUT
constexpr int GG  = 4;
constexpr int CPG = 64;
constexpr int HHH = 56;
constexpr int WWW = 56;
constexpr int HWs = HHH * WWW;         // 3136 = 49*64
constexpr long CHW = (long)256 * HWs;  // 802816
constexpr int NC  = (TT - 1) * 9;      // 63
constexpr long CORR_ELEMS = (long)NBb * GG * NC * HWs;
constexpr long WX_ELEMS   = (long)NBb * GG * (TOo * TT) * HWs;
}

// ---------------------------------------------------------------------------
// Kernel 1: 9-way shifted correlation; one wave per (n, g, t, h-pair).
// h-block=2: b-frame rows h0-1,h0,h1,h1+1 serve both output rows (6 loads/c
// for 2 rows vs 8 before). XCD swizzle keeps all h of one (n,g,t) on one XCD.
// ---------------------------------------------------------------------------
__global__ __launch_bounds__(64, 6)
void corr2_k(const float* __restrict__ x, float* __restrict__ corr)
{
    // nwg = 196*4*8 = 6272; per-XCD contiguous span of 784
    const int lid = blockIdx.x + 196 * (blockIdx.y + 4 * blockIdx.z);
    const int wg  = (lid & 7) * 784 + (lid >> 3);
    int r  = wg;
    const int hb = r % 28; r /= 28;        // h-pair
    const int t  = r % 7;  r /= 7;
    const int g  = r % 4;  r /= 4;
    const int n  = r;

    const int h0 = hb * 2, h1 = h0 + 1;
    const int w  = threadIdx.x;
    const int wc = w < WWW - 1 ? w : WWW - 1;    // right replication pad
    const int rm = h0 > 0 ? h0 - 1 : 0;          // top pad (only hb==0)
    const int rp = h1 < HHH - 1 ? h1 + 1 : HHH - 1;  // bottom pad (only hb==27)

    const float* xa = x + (long)n * TT * CHW + (long)g * CPG * HWs + (long)t * CHW;
    const float* xb = xa + CHW;                  // frame t+1
    const int o0 = h0 * WWW + wc, o1 = h1 * WWW + wc;
    const int om = rm * WWW + wc, op = rp * WWW + wc;

    float accA[9], accB[9];
#pragma unroll
    for (int k = 0; k < 9; ++k) { accA[k] = 0.0f; accB[k] = 0.0f; }

#pragma unroll 4
    for (int c = 0; c < CPG; ++c) {
        const long co = (long)c * HWs;
        const float a0 = xa[co + o0];
        const float a1 = xa[co + o1];
        const float r0 = xb[co + om];   // row h0-1 (clamped)
        const float r1 = xb[co + o0];   // row h0
        const float r2 = xb[co + o1];   // row h1
        const float r3 = xb[co + op];   // row h1+1 (clamped)
        float r0l = __shfl_up(r0, 1), r0r = __shfl_down(r0, 1);
        float r1l = __shfl_up(r1, 1), r1r = __shfl_down(r1, 1);
        float r2l = __shfl_up(r2, 1), r2r = __shfl_down(r2, 1);
        float r3l = __shfl_up(r3, 1), r3r = __shfl_down(r3, 1);
        if (w == 0) { r0l = r0; r1l = r1; r2l = r2; r3l = r3; }
        // right edge: lane 55 pulls lane 56 which holds the clamped col-55 value
        accA[0] = fmaf(a0, r0l, accA[0]); accA[1] = fmaf(a0, r0, accA[1]); accA[2] = fmaf(a0, r0r, accA[2]);
        accA[3] = fmaf(a0, r1l, accA[3]); accA[4] = fmaf(a0, r1, accA[4]); accA[5] = fmaf(a0, r1r, accA[5]);
        accA[6] = fmaf(a0, r2l, accA[6]); accA[7] = fmaf(a0, r2, accA[7]); accA[8] = fmaf(a0, r2r, accA[8]);
        accB[0] = fmaf(a1, r1l, accB[0]); accB[1] = fmaf(a1, r1, accB[1]); accB[2] = fmaf(a1, r1r, accB[2]);
        accB[3] = fmaf(a1, r2l, accB[3]); accB[4] = fmaf(a1, r2, accB[4]); accB[5] = fmaf(a1, r2r, accB[5]);
        accB[6] = fmaf(a1, r3l, accB[6]); accB[7] = fmaf(a1, r3, accB[7]); accB[8] = fmaf(a1, r3r, accB[8]);
    }

    if (w < WWW) {
        float* co = corr + ((((long)n * GG + g) * 7 + t) * 9) * HWs + w;
#pragma unroll
        for (int k = 0; k < 9; ++k) {
            co[(long)k * HWs + h0 * WWW] = accA[k];
            co[(long)k * HWs + h1 * WWW] = accB[k];
        }
    }
}

// ---------------------------------------------------------------------------
// Kernel 2: grouped 1x1 conv per pixel (63 -> 16 outs per wave, och split x4).
// Pixel-flattened: lane = pixel, all 64 lanes active, 256B accesses.
// XCD swizzle: och-siblings (sharing corr reads) on the same XCD.
// ---------------------------------------------------------------------------
__global__ __launch_bounds__(64, 4)
void conv_k(const float* __restrict__ corr,
            const float* __restrict__ conv_w, const float* __restrict__ conv_b,
            float* __restrict__ wxws)
{
    // nwg = 49*16*8 = 6272; per-XCD span 784
    const int lid = blockIdx.x + 49 * (blockIdx.y + 16 * blockIdx.z);
    const int wg  = (lid & 7) * 784 + (lid >> 3);
    int r = wg;
    const int och = r % 4;  r /= 4;
    const int bx  = r % 49; r /= 49;
    const int g   = r % 4;  r /= 4;
    const int n   = r;

    const int pix = bx * 64 + threadIdx.x;

    const float* cbase = corr + (((long)n * GG + g) * NC) * HWs + pix;
    float cr[NC];
#pragma unroll
    for (int i = 0; i < NC; ++i) cr[i] = cbase[(long)i * HWs];

    const float* cw = conv_w + (long)g * (TOo * TT) * NC;
    const float* cb = conv_b + g * (TOo * TT);
    float* wbase = wxws + (((long)n * GG + g) * (TOo * TT)) * HWs + pix;

#pragma unroll
    for (int oo = 0; oo < 16; ++oo) {
        const int o = och * 16 + oo;
        float s = cb[o];
#pragma unroll
        for (int i = 0; i < NC; ++i) s = fmaf(cw[o * NC + i], cr[i], s);
        wbase[(long)o * HWs] = s;
    }
}

// ---------------------------------------------------------------------------
// Kernel 3: weighted segment-sum + residual, pixel-flattened.
// XCD swizzle: cch-siblings (sharing wx reads) on the same XCD.
// ---------------------------------------------------------------------------
__global__ __launch_bounds__(64, 4)
void seg_k(const float* __restrict__ x, const float* __restrict__ wxws,
           float* __restrict__ out)
{
    // nwg = 49*32*8 = 12544; per-XCD span 1568
    const int lid = blockIdx.x + 49 * (blockIdx.y + 32 * blockIdx.z);
    const int wg  = (lid & 7) * 1568 + (lid >> 3);
    int r = wg;
    const int cch = r % 8;  r /= 8;
    const int bx  = r % 49; r /= 49;
    const int g   = r % 4;  r /= 4;
    const int n   = r;

    const int pix = bx * 64 + threadIdx.x;

    const float* wbase = wxws + (((long)n * GG + g) * (TOo * TT)) * HWs + pix;
    float wxr[TOo * TT];
#pragma unroll
    for (int o = 0; o < TOo * TT; ++o) wxr[o] = wbase[(long)o * HWs];

    const float* xn = x   + (long)n * TT  * CHW;
    float*       on = out + (long)n * TOo * CHW;

#pragma unroll
    for (int cpi = 0; cpi < 8; ++cpi) {
        const int cp = cch * 8 + cpi;
        const float* xc = xn + (long)(cp * GG + g) * HWs + pix;
        float xv[TT];
#pragma unroll
        for (int t = 0; t < TT; ++t) xv[t] = xc[(long)t * CHW];
        float* oc = on + (long)(g * CPG + cp) * HWs + pix;
#pragma unroll
        for (int to = 0; to < TOo; ++to) {
            float s = xv[to];   // residual (i_in[to] == to)
#pragma unroll
            for (int t = 0; t < TT; ++t) s = fmaf(wxr[to * TT + t], xv[t], s);
            oc[(long)to * CHW] = s;
        }
    }
}

// ---------------------------------------------------------------------------
// Fallback (tiny ws): proven single-kernel R1 version.
// ---------------------------------------------------------------------------
__global__ __launch_bounds__(64, 2)
void corr_fusion_mono(const float* __restrict__ x,
                      const float* __restrict__ conv_w,
                      const float* __restrict__ conv_b,
                      float* __restrict__ out)
{
    const int w  = threadIdx.x;
    const int wc = w < WWW - 1 ? w : WWW - 1;
    const int h  = blockIdx.x;
    const int g  = blockIdx.y;
    const int n  = blockIdx.z;
    const int hm = h > 0 ? h - 1 : 0;
    const int hp = h < HHH - 1 ? h + 1 : HHH - 1;

    const int offh = h  * WWW + wc;
    const int offm = hm * WWW + wc;
    const int offp = hp * WWW + wc;

    float corr[NC];
#pragma unroll
    for (int i = 0; i < NC; ++i) corr[i] = 0.0f;

    const float* xg = x + (long)n * TT * CHW + (long)g * CPG * HWs;

    for (int c = 0; c < CPG; ++c) {
        const float* xc = xg + (long)c * HWs;
        float rh[TT], rm[TT - 1], rp[TT - 1];
#pragma unroll
        for (int t = 0; t < TT; ++t) rh[t] = xc[(long)t * CHW + offh];
#pragma unroll
        for (int t = 1; t < TT; ++t) {
            rm[t - 1] = xc[(long)t * CHW + offm];
            rp[t - 1] = xc[(long)t * CHW + offp];
        }
#pragma unroll
        for (int t = 0; t < TT - 1; ++t) {
            const float a = rh[t];
#pragma unroll
            for (int di = 0; di < 3; ++di) {
                float bc = (di == 0) ? rm[t] : (di == 1) ? rh[t + 1] : rp[t];
                float bl = __shfl_up(bc, 1);
                if (w == 0) bl = bc;
                float br = __shfl_down(bc, 1);
                if (w == WWW - 1) br = bc;
                const int base = t * 9 + di * 3;
                corr[base + 0] = fmaf(a, bl, corr[base + 0]);
                corr[base + 1] = fmaf(a, bc, corr[base + 1]);
                corr[base + 2] = fmaf(a, br, corr[base + 2]);
            }
        }
    }

    const float* cw = conv_w + (long)g * (TOo * TT) * NC;
    const float* cb = conv_b + g * (TOo * TT);
    float wx[TOo * TT];
#pragma unroll
    for (int o = 0; o < TOo * TT; ++o) {
        float s = cb[o];
#pragma unroll
        for (int i = 0; i < NC; ++i) s = fmaf(cw[o * NC + i], corr[i], s);
        wx[o] = s;
    }

    const float* xn = x   + (long)n * TT  * CHW;
    float*       on = out + (long)n * TOo * CHW;
    for (int cp = 0; cp < CPG; ++cp) {
        const float* xc = xn + (long)(cp * GG + g) * HWs + offh;
        float xv[TT];
#pragma unroll
        for (int t = 0; t < TT; ++t) xv[t] = xc[(long)t * CHW];
        if (w < WWW) {
            float* oc = on + (long)(g * CPG + cp) * HWs + h * WWW + w;
#pragma unroll
            for (int to = 0; to < TOo; ++to) {
                float s = xv[to];
#pragma unroll
                for (int t = 0; t < TT; ++t) s = fmaf(wx[to * TT + t], xv[t], s);
                oc[(long)to * CHW] = s;
            }
        }
    }
}

extern "C" void kernel_launch(void* const* d_in, const int* in_sizes, int n_in,
                              void* d_out, int out_size, void* d_ws, size_t ws_size,
                              hipStream_t stream) {
    const float* x  = (const float*)d_in[0];
    const float* cw = (const float*)d_in[1];
    const float* cb = (const float*)d_in[2];
    float* out = (float*)d_out;

    if (ws_size >= (CORR_ELEMS + WX_ELEMS) * sizeof(float)) {
        float* corr = (float*)d_ws;
        float* wxws = corr + CORR_ELEMS;
        dim3 gridA(196, GG, NBb);            // 6272 single-wave blocks (t, h-pair)
        hipLaunchKernelGGL(corr2_k, gridA, dim3(64), 0, stream, x, corr);
        dim3 gridC(49, GG * 4, NBb);         // 6272 single-wave blocks
        hipLaunchKernelGGL(conv_k, gridC, dim3(64), 0, stream, corr, cw, cb, wxws);
        dim3 gridS(49, GG * 8, NBb);         // 12544 single-wave blocks
        hipLaunchKernelGGL(seg_k, gridS, dim3(64), 0, stream, x, wxws, out);
    } else {
        dim3 grid(HHH, GG, NBb);
        hipLaunchKernelGGL(corr_fusion_mono, grid, dim3(64), 0, stream, x, cw, cb, out);
    }
}